// Round 16
// baseline (648.166 us; speedup 1.0000x reference)
//
#include <hip/hip_runtime.h>
#include <hip/hip_bf16.h>

// MiniMax MoE top-2, MI355X. T=2048, H=2048, F=4096, E=8.
// Round 16: R12 base (best 575us) + depth-1 B-register rotation in both
// GEMMs (B(kt+1) issued after barrier (b), flies under MFMA; A stays
// global_load_lds so rotation costs only 16 VGPR). gemm1 bounds (512,3).

#define T_TOK 2048
#define H_DIM 2048
#define F_DIM 4096
#define E_NUM 8
#define NPAIR (T_TOK * 2)

typedef __attribute__((ext_vector_type(8))) short short8;
typedef __attribute__((ext_vector_type(4))) float f32x4;

__device__ __forceinline__ unsigned short f2bf(float f) {
    unsigned u = __builtin_bit_cast(unsigned, f);
    u = (u + 0x7FFFu + ((u >> 16) & 1u)) >> 16;   // RNE
    return (unsigned short)u;
}

__device__ __forceinline__ uint4 pack8(float4 a, float4 b) {
    uint4 o;
    o.x = f2bf(a.x) | ((unsigned)f2bf(a.y) << 16);
    o.y = f2bf(a.z) | ((unsigned)f2bf(a.w) << 16);
    o.z = f2bf(b.x) | ((unsigned)f2bf(b.y) << 16);
    o.w = f2bf(b.z) | ((unsigned)f2bf(b.w) << 16);
    return o;
}

__device__ __forceinline__ uint2 pack4(float4 a) {
    uint2 o;
    o.x = f2bf(a.x) | ((unsigned)f2bf(a.y) << 16);
    o.y = f2bf(a.z) | ((unsigned)f2bf(a.w) << 16);
    return o;
}

__device__ __forceinline__ void gload16(const void* g, void* s) {
    __builtin_amdgcn_global_load_lds(
        (const __attribute__((address_space(1))) unsigned int*)g,
        (__attribute__((address_space(3))) unsigned int*)s, 16, 0, 0);
}

// ---- x fp32 -> bf16 ----------------------------------------------------
__global__ void k_cvt_x(const float* __restrict__ x, ushort* __restrict__ xb) {
    int i = blockIdx.x * blockDim.x + threadIdx.x;
    const float4* p = (const float4*)x + (size_t)i * 2;
    uint2 lo = pack4(p[0]), hi = pack4(p[1]);
    ((uint4*)xb)[i] = make_uint4(lo.x, lo.y, hi.x, hi.y);
}

// ---- router ------------------------------------------------------------
__global__ void k_router(const float* __restrict__ x, const float* __restrict__ gw,
                         int2* __restrict__ eidx, float2* __restrict__ ew,
                         int* __restrict__ cnt) {
    int t = blockIdx.x * 4 + (threadIdx.x >> 6);
    int lane = threadIdx.x & 63;
    const float* xr = x + (size_t)t * H_DIM;
    float l[E_NUM];
    #pragma unroll
    for (int e = 0; e < E_NUM; e++) {
        const float* wr = gw + (size_t)e * H_DIM;
        float acc = 0.f;
        for (int i = lane; i < H_DIM; i += 64) acc += xr[i] * wr[i];
        #pragma unroll
        for (int o = 32; o; o >>= 1) acc += __shfl_xor(acc, o);
        l[e] = acc;
    }
    if (lane == 0) {
        int e0 = 0;
        #pragma unroll
        for (int e = 1; e < E_NUM; e++) if (l[e] > l[e0]) e0 = e;
        int e1 = -1;
        #pragma unroll
        for (int e = 0; e < E_NUM; e++) {
            if (e == e0) continue;
            if (e1 < 0 || l[e] > l[e1]) e1 = e;
        }
        float s1 = expf(l[e1] - l[e0]);
        float w0 = 1.f / (1.f + s1);
        float w1 = s1 * w0;
        eidx[t] = make_int2(e0, e1);
        ew[t]   = make_float2(w0, w1);
        atomicAdd(&cnt[e0], 1);
        atomicAdd(&cnt[e1], 1);
    }
}

__global__ void k_off(const int* __restrict__ cnt, int* __restrict__ off,
                      int* __restrict__ cnt2) {
    if (threadIdx.x == 0) {
        int s = 0;
        for (int e = 0; e < E_NUM; e++) { off[e] = s; s += cnt[e]; cnt2[e] = 0; }
        off[E_NUM] = s;
    }
}

__global__ void k_fill(const int2* __restrict__ eidx, const float2* __restrict__ ew,
                       const int* __restrict__ off, int* __restrict__ cnt2,
                       int* __restrict__ ptok, int2* __restrict__ inv) {
    int t = blockIdx.x * blockDim.x + threadIdx.x;
    if (t >= T_TOK) return;
    int2 e = eidx[t];
    int p0 = off[e.x] + atomicAdd(&cnt2[e.x], 1);
    ptok[p0] = t;
    int p1 = off[e.y] + atomicAdd(&cnt2[e.y], 1);
    ptok[p1] = t;
    inv[t] = make_int2(p0, p1);
}

// ---- grouped GEMM1: h = silu(X Wg^T) * (X Wu^T) ------------------------
// BM=256 x BN=64 x BK=64, 512 thr = 8 waves (4m x 2n), wave tile 64x32.
// A: global_load_lds. B: rotated reg-prefetch (16 VGPR), proven 0-conflict map.
__global__ __launch_bounds__(512, 3) void k_gemm1(
        const ushort* __restrict__ xb, const float* __restrict__ wg,
        const float* __restrict__ wu, const int* __restrict__ ptok,
        const int* __restrict__ off, ushort* __restrict__ hbuf) {
    __shared__ __align__(16) ushort As[256 * 64];   // 32 KB
    __shared__ __align__(16) ushort Bg[64 * 64];    //  8 KB
    __shared__ __align__(16) ushort Bu[64 * 64];    //  8 KB

    int e = blockIdx.y >> 3, mt = blockIdx.y & 7;
    int base = off[e], ne = off[e + 1] - base;
    int row0 = mt * 256;
    if (row0 >= ne) return;
    int nb = blockIdx.x * 64;

    int tid = threadIdx.x;
    int wv = tid >> 6, l = tid & 63;
    int lr = l & 15, lk = l >> 4;
    int wm = wv >> 1, wn = wv & 1;

    int wvu = __builtin_amdgcn_readfirstlane(wv);
    const ushort* srcA[4];
    int sslot = 8 * ((l & 7) ^ ((l >> 3) & 7));
    #pragma unroll
    for (int c = 0; c < 4; c++) {
        int r = (wvu * 4 + c) * 8 + (l >> 3);
        int pp = base + min(row0 + r, ne - 1);
        srcA[c] = xb + (size_t)ptok[pp] * H_DIM + sslot;
    }

    int brow = tid >> 3, bs = tid & 7;
    const float* wgrow = wg + ((size_t)e * F_DIM + nb + brow) * H_DIM + bs * 8;
    const float* wurow = wu + ((size_t)e * F_DIM + nb + brow) * H_DIM + bs * 8;
    int bo = brow * 64 + (((bs * 16) ^ ((brow & 7) << 4)) >> 1);

    int rsw = (lr & 7) << 4;

    f32x4 accg[4][2] = {}; f32x4 accu[4][2] = {};

    // prologue: B(0) -> regs (16 VGPR)
    float4 pg0 = *(const float4*)(wgrow);
    float4 pg1 = *(const float4*)(wgrow + 4);
    float4 pu0 = *(const float4*)(wurow);
    float4 pu1 = *(const float4*)(wurow + 4);

    const int NT = H_DIM / 64;
    for (int kt = 0; kt < NT; kt++) {
        int kb = kt * 64;
        __syncthreads();                       // (a): drains B(kt) regs + prev MFMA
        #pragma unroll
        for (int c = 0; c < 4; c++)
            gload16(srcA[c] + kb, (ushort*)As + (wvu * 4 + c) * 512);
        *(uint4*)(&Bg[bo]) = pack8(pg0, pg1);
        *(uint4*)(&Bu[bo]) = pack8(pu0, pu1);
        __syncthreads();                       // (b): A(kt) + ds_writes visible
        if (kt + 1 < NT) {                     // issue B(kt+1): hides under MFMA
            int kn = kb + 64;
            pg0 = *(const float4*)(wgrow + kn);
            pg1 = *(const float4*)(wgrow + kn + 4);
            pu0 = *(const float4*)(wurow + kn);
            pu1 = *(const float4*)(wurow + kn + 4);
        }
        __builtin_amdgcn_s_setprio(1);
        #pragma unroll
        for (int kk = 0; kk < 2; kk++) {
            int kby = kk * 64 + lk * 16;
            short8 a[4];
            #pragma unroll
            for (int m = 0; m < 4; m++) {
                int row = wm * 64 + m * 16 + lr;
                a[m] = *(const short8*)(&As[(row * 128 + (kby ^ rsw)) >> 1]);
            }
            #pragma unroll
            for (int n = 0; n < 2; n++) {
                int rowb = wn * 32 + n * 16 + lr;
                int boff = (rowb * 128 + (kby ^ rsw)) >> 1;
                short8 bg8 = *(const short8*)(&Bg[boff]);
                short8 bu8 = *(const short8*)(&Bu[boff]);
                #pragma unroll
                for (int m = 0; m < 4; m++) {
                    accg[m][n] = __builtin_amdgcn_mfma_f32_16x16x32_bf16(a[m], bg8, accg[m][n], 0, 0, 0);
                    accu[m][n] = __builtin_amdgcn_mfma_f32_16x16x32_bf16(a[m], bu8, accu[m][n], 0, 0, 0);
                }
            }
        }
        __builtin_amdgcn_s_setprio(0);
    }

    #pragma unroll
    for (int m = 0; m < 4; m++) {
        #pragma unroll
        for (int r = 0; r < 4; r++) {
            int lrow = wm * 64 + m * 16 + lk * 4 + r;
            if (row0 + lrow < ne) {
                size_t rb = (size_t)(base + row0 + lrow) * F_DIM + nb;
                #pragma unroll
                for (int n = 0; n < 2; n++) {
                    float g = accg[m][n][r], u = accu[m][n][r];
                    float hv = g / (1.f + __expf(-g)) * u;
                    hbuf[rb + wn * 32 + n * 16 + lr] = f2bf(hv);
                }
            }
        }
    }
}

// ---- grouped GEMM2: ybuf[p] = h[p] Wd^T --------------------------------
// BM=256 x BN=128 x BK=64, 512 thr = 8 waves (4m x 2n), wave tile 64x64.
// A: global_load_lds. B: rotated reg-prefetch (16 VGPR).
__global__ __launch_bounds__(512, 2) void k_gemm2(
        const ushort* __restrict__ hbuf, const float* __restrict__ wd,
        const int* __restrict__ off, float* __restrict__ ybuf) {
    __shared__ __align__(16) ushort As[256 * 64];   // 32 KB
    __shared__ __align__(16) ushort Bs[128 * 64];   // 16 KB

    int e = blockIdx.y >> 3, mt = blockIdx.y & 7;
    int base = off[e], ne = off[e + 1] - base;
    int row0 = mt * 256;
    if (row0 >= ne) return;
    int nb = blockIdx.x * 128;

    int tid = threadIdx.x;
    int wv = tid >> 6, l = tid & 63;
    int lr = l & 15, lk = l >> 4;
    int wm = wv >> 1, wn = wv & 1;

    int wvu = __builtin_amdgcn_readfirstlane(wv);
    const ushort* srcA[4];
    int sslot = 8 * ((l & 7) ^ ((l >> 3) & 7));
    #pragma unroll
    for (int c = 0; c < 4; c++) {
        int r = (wvu * 4 + c) * 8 + (l >> 3);
        int pp = base + min(row0 + r, ne - 1);
        srcA[c] = hbuf + (size_t)pp * F_DIM + sslot;
    }

    int brow = tid >> 2, bs = tid & 3;
    const float* wdrow = wd + ((size_t)e * H_DIM + nb + brow) * F_DIM + bs * 16;
    int bsw = (brow & 7) << 4;
    int bo0 = brow * 64 + (((bs * 32) ^ bsw) >> 1);
    int bo1 = brow * 64 + (((bs * 32 + 16) ^ bsw) >> 1);

    int rsw = (lr & 7) << 4;

    f32x4 acc[4][4] = {};

    // prologue: B(0) -> regs (16 VGPR)
    float4 pb0 = *(const float4*)(wdrow);
    float4 pb1 = *(const float4*)(wdrow + 4);
    float4 pb2 = *(const float4*)(wdrow + 8);
    float4 pb3 = *(const float4*)(wdrow + 12);

    const int NT = F_DIM / 64;
    for (int kt = 0; kt < NT; kt++) {
        int kb = kt * 64;
        __syncthreads();                       // (a)
        #pragma unroll
        for (int c = 0; c < 4; c++)
            gload16(srcA[c] + kb, (ushort*)As + (wvu * 4 + c) * 512);
        *(uint4*)(&Bs[bo0]) = pack8(pb0, pb1);
        *(uint4*)(&Bs[bo1]) = pack8(pb2, pb3);
        __syncthreads();                       // (b)
        if (kt + 1 < NT) {
            int kn = kb + 64;
            pb0 = *(const float4*)(wdrow + kn);
            pb1 = *(const float4*)(wdrow + kn + 4);
            pb2 = *(const float4*)(wdrow + kn + 8);
            pb3 = *(const float4*)(wdrow + kn + 12);
        }
        __builtin_amdgcn_s_setprio(1);
        #pragma unroll
        for (int kk = 0; kk < 2; kk++) {
            int kby = kk * 64 + lk * 16;
            short8 a[4];
            #pragma unroll
            for (int m = 0; m < 4; m++) {
                int row = wm * 64 + m * 16 + lr;
                a[m] = *(const short8*)(&As[(row * 128 + (kby ^ rsw)) >> 1]);
            }
            #pragma unroll
            for (int n = 0; n < 4; n++) {
                int rowb = wn * 64 + n * 16 + lr;
                short8 b8 = *(const short8*)(&Bs[(rowb * 128 + (kby ^ rsw)) >> 1]);
                #pragma unroll
                for (int m = 0; m < 4; m++)
                    acc[m][n] = __builtin_amdgcn_mfma_f32_16x16x32_bf16(a[m], b8, acc[m][n], 0, 0, 0);
            }
        }
        __builtin_amdgcn_s_setprio(0);
    }

    #pragma unroll
    for (int m = 0; m < 4; m++) {
        #pragma unroll
        for (int r = 0; r < 4; r++) {
            int lrow = wm * 64 + m * 16 + lk * 4 + r;
            if (row0 + lrow < ne) {
                float* yrow = ybuf + (size_t)(base + row0 + lrow) * H_DIM + nb;
                #pragma unroll
                for (int n = 0; n < 4; n++)
                    yrow[wn * 64 + n * 16 + lr] = acc[m][n][r];
            }
        }
    }
}

// ---- combine: out[t] = w0*y[p0] + w1*y[p1] -----------------------------
__global__ void k_combine(const float* __restrict__ ybuf,
                          const float2* __restrict__ ew,
                          const int2* __restrict__ inv,
                          float* __restrict__ out) {
    int t = blockIdx.x;
    float2 w = ew[t];
    int2 pp = inv[t];
    const float4* y0 = (const float4*)(ybuf + (size_t)pp.x * H_DIM);
    const float4* y1 = (const float4*)(ybuf + (size_t)pp.y * H_DIM);
    float4* o = (float4*)(out + (size_t)t * H_DIM);
    for (int j = threadIdx.x; j < H_DIM / 4; j += blockDim.x) {
        float4 a = y0[j], b = y1[j];
        float4 r;
        r.x = w.x * a.x + w.y * b.x;
        r.y = w.x * a.y + w.y * b.y;
        r.z = w.x * a.z + w.y * b.z;
        r.w = w.x * a.w + w.y * b.w;
        o[j] = r;
    }
}

extern "C" void kernel_launch(void* const* d_in, const int* in_sizes, int n_in,
                              void* d_out, int out_size, void* d_ws, size_t ws_size,
                              hipStream_t stream) {
    const float* x  = (const float*)d_in[0];
    const float* gw = (const float*)d_in[1];
    const float* wg = (const float*)d_in[2];
    const float* wu = (const float*)d_in[3];
    const float* wd = (const float*)d_in[4];
    float* out = (float*)d_out;

    char* ws = (char*)d_ws;
    size_t o = 0;
    ushort* xb   = (ushort*)(ws + o); o += (size_t)T_TOK * H_DIM * 2;   //  8 MB
    ushort* hbuf = (ushort*)(ws + o); o += (size_t)NPAIR * F_DIM * 2;   // 32 MB
    float*  ybuf = (float*) (ws + o); o += (size_t)NPAIR * H_DIM * 4;   // 32 MB
    int*    ptok = (int*)   (ws + o); o += NPAIR * 4;
    int2*   eidx = (int2*)  (ws + o); o += T_TOK * 8;
    float2* ew   = (float2*)(ws + o); o += T_TOK * 8;
    int2*   inv  = (int2*)  (ws + o); o += T_TOK * 8;
    int*    cnt  = (int*)   (ws + o); o += 256;
    int*    cnt2 = (int*)   (ws + o); o += 256;
    int*    off  = (int*)   (ws + o); o += 256;

    hipMemsetAsync(cnt, 0, 256, stream);

    k_cvt_x <<<T_TOK * H_DIM / 8 / 256, 256, 0, stream>>>(x, xb);
    k_router<<<T_TOK / 4, 256, 0, stream>>>(x, gw, eidx, ew, cnt);
    k_off   <<<1, 64, 0, stream>>>(cnt, off, cnt2);
    k_fill  <<<T_TOK / 256, 256, 0, stream>>>(eidx, ew, off, cnt2, ptok, inv);

    dim3 g1(F_DIM / 64, E_NUM * 8);      // x: ntile(64), y: e*8 + mtile(256)
    k_gemm1<<<g1, 512, 0, stream>>>(xb, wg, wu, ptok, off, hbuf);
    dim3 g2(H_DIM / 128, E_NUM * 8);     // x: ntile(128), y: e*8 + mtile(256)
    k_gemm2<<<g2, 512, 0, stream>>>(hbuf, wd, off, ybuf);
    k_combine<<<T_TOK, 256, 0, stream>>>(ybuf, ew, inv, out);
}

// Round 17
// 573.357 us; speedup vs baseline: 1.1305x; 1.1305x over previous
//
#include <hip/hip_runtime.h>
#include <hip/hip_bf16.h>

// MiniMax MoE top-2, MI355X. T=2048, H=2048, F=4096, E=8.
// Round 17: R12-exact bodies (best 575us). gemm2 split-K x2 WITHOUT atomics:
// each K-half writes partials to its own ybuf half (plain stores, no memset);
// combine sums halves in fixed order. Live blocks 256->512 (2/CU), exactly
// replicating R11 gemm1t's 185us configuration.

#define T_TOK 2048
#define H_DIM 2048
#define F_DIM 4096
#define E_NUM 8
#define NPAIR (T_TOK * 2)

typedef __attribute__((ext_vector_type(8))) short short8;
typedef __attribute__((ext_vector_type(4))) float f32x4;

__device__ __forceinline__ unsigned short f2bf(float f) {
    unsigned u = __builtin_bit_cast(unsigned, f);
    u = (u + 0x7FFFu + ((u >> 16) & 1u)) >> 16;   // RNE
    return (unsigned short)u;
}

__device__ __forceinline__ uint4 pack8(float4 a, float4 b) {
    uint4 o;
    o.x = f2bf(a.x) | ((unsigned)f2bf(a.y) << 16);
    o.y = f2bf(a.z) | ((unsigned)f2bf(a.w) << 16);
    o.z = f2bf(b.x) | ((unsigned)f2bf(b.y) << 16);
    o.w = f2bf(b.z) | ((unsigned)f2bf(b.w) << 16);
    return o;
}

__device__ __forceinline__ uint2 pack4(float4 a) {
    uint2 o;
    o.x = f2bf(a.x) | ((unsigned)f2bf(a.y) << 16);
    o.y = f2bf(a.z) | ((unsigned)f2bf(a.w) << 16);
    return o;
}

__device__ __forceinline__ void gload16(const void* g, void* s) {
    __builtin_amdgcn_global_load_lds(
        (const __attribute__((address_space(1))) unsigned int*)g,
        (__attribute__((address_space(3))) unsigned int*)s, 16, 0, 0);
}

// ---- x fp32 -> bf16 ----------------------------------------------------
__global__ void k_cvt_x(const float* __restrict__ x, ushort* __restrict__ xb) {
    int i = blockIdx.x * blockDim.x + threadIdx.x;
    const float4* p = (const float4*)x + (size_t)i * 2;
    uint2 lo = pack4(p[0]), hi = pack4(p[1]);
    ((uint4*)xb)[i] = make_uint4(lo.x, lo.y, hi.x, hi.y);
}

// ---- router ------------------------------------------------------------
__global__ void k_router(const float* __restrict__ x, const float* __restrict__ gw,
                         int2* __restrict__ eidx, float2* __restrict__ ew,
                         int* __restrict__ cnt) {
    int t = blockIdx.x * 4 + (threadIdx.x >> 6);
    int lane = threadIdx.x & 63;
    const float* xr = x + (size_t)t * H_DIM;
    float l[E_NUM];
    #pragma unroll
    for (int e = 0; e < E_NUM; e++) {
        const float* wr = gw + (size_t)e * H_DIM;
        float acc = 0.f;
        for (int i = lane; i < H_DIM; i += 64) acc += xr[i] * wr[i];
        #pragma unroll
        for (int o = 32; o; o >>= 1) acc += __shfl_xor(acc, o);
        l[e] = acc;
    }
    if (lane == 0) {
        int e0 = 0;
        #pragma unroll
        for (int e = 1; e < E_NUM; e++) if (l[e] > l[e0]) e0 = e;
        int e1 = -1;
        #pragma unroll
        for (int e = 0; e < E_NUM; e++) {
            if (e == e0) continue;
            if (e1 < 0 || l[e] > l[e1]) e1 = e;
        }
        float s1 = expf(l[e1] - l[e0]);
        float w0 = 1.f / (1.f + s1);
        float w1 = s1 * w0;
        eidx[t] = make_int2(e0, e1);
        ew[t]   = make_float2(w0, w1);
        atomicAdd(&cnt[e0], 1);
        atomicAdd(&cnt[e1], 1);
    }
}

__global__ void k_off(const int* __restrict__ cnt, int* __restrict__ off,
                      int* __restrict__ cnt2) {
    if (threadIdx.x == 0) {
        int s = 0;
        for (int e = 0; e < E_NUM; e++) { off[e] = s; s += cnt[e]; cnt2[e] = 0; }
        off[E_NUM] = s;
    }
}

__global__ void k_fill(const int2* __restrict__ eidx, const float2* __restrict__ ew,
                       const int* __restrict__ off, int* __restrict__ cnt2,
                       int* __restrict__ ptok, int2* __restrict__ inv) {
    int t = blockIdx.x * blockDim.x + threadIdx.x;
    if (t >= T_TOK) return;
    int2 e = eidx[t];
    int p0 = off[e.x] + atomicAdd(&cnt2[e.x], 1);
    ptok[p0] = t;
    int p1 = off[e.y] + atomicAdd(&cnt2[e.y], 1);
    ptok[p1] = t;
    inv[t] = make_int2(p0, p1);
}

// ---- grouped GEMM1: h = silu(X Wg^T) * (X Wu^T)  (R12-exact) -----------
// BM=256 x BN=64 x BK=64, 512 thr = 8 waves (4m x 2n), wave tile 64x32.
__global__ __launch_bounds__(512, 4) void k_gemm1(
        const ushort* __restrict__ xb, const float* __restrict__ wg,
        const float* __restrict__ wu, const int* __restrict__ ptok,
        const int* __restrict__ off, ushort* __restrict__ hbuf) {
    __shared__ __align__(16) ushort As[256 * 64];   // 32 KB
    __shared__ __align__(16) ushort Bg[64 * 64];    //  8 KB
    __shared__ __align__(16) ushort Bu[64 * 64];    //  8 KB

    int e = blockIdx.y >> 4, mt = blockIdx.y & 15;
    int base = off[e], ne = off[e + 1] - base;
    int row0 = mt * 256;
    if (row0 >= ne) return;
    int nb = blockIdx.x * 64;

    int tid = threadIdx.x;
    int wv = tid >> 6, l = tid & 63;
    int lr = l & 15, lk = l >> 4;
    int wm = wv >> 1, wn = wv & 1;

    int wvu = __builtin_amdgcn_readfirstlane(wv);
    const ushort* srcA[4];
    int sslot = 8 * ((l & 7) ^ ((l >> 3) & 7));
    #pragma unroll
    for (int c = 0; c < 4; c++) {
        int r = (wvu * 4 + c) * 8 + (l >> 3);
        int pp = base + min(row0 + r, ne - 1);
        srcA[c] = xb + (size_t)ptok[pp] * H_DIM + sslot;
    }

    int brow = tid >> 3, bs = tid & 7;
    const float* wgrow = wg + ((size_t)e * F_DIM + nb + brow) * H_DIM + bs * 8;
    const float* wurow = wu + ((size_t)e * F_DIM + nb + brow) * H_DIM + bs * 8;
    int bo = brow * 64 + (((bs * 16) ^ ((brow & 7) << 4)) >> 1);

    int rsw = (lr & 7) << 4;

    f32x4 accg[4][2] = {}; f32x4 accu[4][2] = {};

    for (int kb = 0; kb < H_DIM; kb += 64) {
        __syncthreads();
        #pragma unroll
        for (int c = 0; c < 4; c++)
            gload16(srcA[c] + kb, (ushort*)As + (wvu * 4 + c) * 512);
        float4 g0 = *(const float4*)(wgrow + kb);
        float4 g1 = *(const float4*)(wgrow + kb + 4);
        *(uint4*)(&Bg[bo]) = pack8(g0, g1);
        float4 u0 = *(const float4*)(wurow + kb);
        float4 u1 = *(const float4*)(wurow + kb + 4);
        *(uint4*)(&Bu[bo]) = pack8(u0, u1);
        __syncthreads();

        #pragma unroll
        for (int kk = 0; kk < 2; kk++) {
            int kby = kk * 64 + lk * 16;
            short8 a[4];
            #pragma unroll
            for (int m = 0; m < 4; m++) {
                int row = wm * 64 + m * 16 + lr;
                a[m] = *(const short8*)(&As[(row * 128 + (kby ^ rsw)) >> 1]);
            }
            #pragma unroll
            for (int n = 0; n < 2; n++) {
                int rowb = wn * 32 + n * 16 + lr;
                int boff = (rowb * 128 + (kby ^ rsw)) >> 1;
                short8 bg8 = *(const short8*)(&Bg[boff]);
                short8 bu8 = *(const short8*)(&Bu[boff]);
                #pragma unroll
                for (int m = 0; m < 4; m++) {
                    accg[m][n] = __builtin_amdgcn_mfma_f32_16x16x32_bf16(a[m], bg8, accg[m][n], 0, 0, 0);
                    accu[m][n] = __builtin_amdgcn_mfma_f32_16x16x32_bf16(a[m], bu8, accu[m][n], 0, 0, 0);
                }
            }
        }
    }

    #pragma unroll
    for (int m = 0; m < 4; m++) {
        #pragma unroll
        for (int r = 0; r < 4; r++) {
            int lrow = wm * 64 + m * 16 + lk * 4 + r;
            if (row0 + lrow < ne) {
                size_t rb = (size_t)(base + row0 + lrow) * F_DIM + nb;
                #pragma unroll
                for (int n = 0; n < 2; n++) {
                    float g = accg[m][n][r], u = accu[m][n][r];
                    float hv = g / (1.f + __expf(-g)) * u;
                    hbuf[rb + wn * 32 + n * 16 + lr] = f2bf(hv);
                }
            }
        }
    }
}

// ---- grouped GEMM2: split-K x2 partials, plain stores ------------------
// BM=256 x BN=128, K = F/2 per block, 512 thr = 8 waves, wave 64x64.
// ybufs[kh] gets partial sums; combine adds halves. 512 live blocks (2/CU).
__global__ __launch_bounds__(512, 2) void k_gemm2(
        const ushort* __restrict__ hbuf, const float* __restrict__ wd,
        const int* __restrict__ off, float* __restrict__ ybufs) {
    __shared__ __align__(16) ushort As[256 * 64];   // 32 KB
    __shared__ __align__(16) ushort Bs[128 * 64];   // 16 KB

    int yy = blockIdx.y;            // yy = e*16 + mt*2 + kh
    int kh = yy & 1;
    int mt = (yy >> 1) & 7;
    int e  = yy >> 4;
    int base = off[e], ne = off[e + 1] - base;
    int row0 = mt * 256;
    if (row0 >= ne) return;
    int nb = blockIdx.x * 128;
    int k0 = kh * (F_DIM / 2);
    float* ybuf = ybufs + (size_t)kh * NPAIR * H_DIM;

    int tid = threadIdx.x;
    int wv = tid >> 6, l = tid & 63;
    int lr = l & 15, lk = l >> 4;
    int wm = wv >> 1, wn = wv & 1;

    int wvu = __builtin_amdgcn_readfirstlane(wv);
    const ushort* srcA[4];
    int sslot = 8 * ((l & 7) ^ ((l >> 3) & 7));
    #pragma unroll
    for (int c = 0; c < 4; c++) {
        int r = (wvu * 4 + c) * 8 + (l >> 3);
        int pp = base + min(row0 + r, ne - 1);
        srcA[c] = hbuf + (size_t)pp * F_DIM + k0 + sslot;
    }

    int brow = tid >> 2, bs = tid & 3;
    const float* wdrow = wd + ((size_t)e * H_DIM + nb + brow) * F_DIM + k0 + bs * 16;
    int bsw = (brow & 7) << 4;
    int bo0 = brow * 64 + (((bs * 32) ^ bsw) >> 1);
    int bo1 = brow * 64 + (((bs * 32 + 16) ^ bsw) >> 1);

    int rsw = (lr & 7) << 4;

    f32x4 acc[4][4] = {};

    for (int kb = 0; kb < F_DIM / 2; kb += 64) {
        __syncthreads();
        #pragma unroll
        for (int c = 0; c < 4; c++)
            gload16(srcA[c] + kb, (ushort*)As + (wvu * 4 + c) * 512);
        float4 b0 = *(const float4*)(wdrow + kb);
        float4 b1 = *(const float4*)(wdrow + kb + 4);
        float4 b2 = *(const float4*)(wdrow + kb + 8);
        float4 b3 = *(const float4*)(wdrow + kb + 12);
        *(uint4*)(&Bs[bo0]) = pack8(b0, b1);
        *(uint4*)(&Bs[bo1]) = pack8(b2, b3);
        __syncthreads();

        #pragma unroll
        for (int kk = 0; kk < 2; kk++) {
            int kby = kk * 64 + lk * 16;
            short8 a[4];
            #pragma unroll
            for (int m = 0; m < 4; m++) {
                int row = wm * 64 + m * 16 + lr;
                a[m] = *(const short8*)(&As[(row * 128 + (kby ^ rsw)) >> 1]);
            }
            #pragma unroll
            for (int n = 0; n < 4; n++) {
                int rowb = wn * 64 + n * 16 + lr;
                short8 b8 = *(const short8*)(&Bs[(rowb * 128 + (kby ^ rsw)) >> 1]);
                #pragma unroll
                for (int m = 0; m < 4; m++)
                    acc[m][n] = __builtin_amdgcn_mfma_f32_16x16x32_bf16(a[m], b8, acc[m][n], 0, 0, 0);
            }
        }
    }

    #pragma unroll
    for (int m = 0; m < 4; m++) {
        #pragma unroll
        for (int r = 0; r < 4; r++) {
            int lrow = wm * 64 + m * 16 + lk * 4 + r;
            if (row0 + lrow < ne) {
                float* yrow = ybuf + (size_t)(base + row0 + lrow) * H_DIM + nb;
                #pragma unroll
                for (int n = 0; n < 4; n++)
                    yrow[wn * 64 + n * 16 + lr] = acc[m][n][r];
            }
        }
    }
}

// ---- combine: out[t] = w0*(y0[p0]+y1[p0]) + w1*(y0[p1]+y1[p1]) ---------
__global__ void k_combine(const float* __restrict__ ybufs,
                          const float2* __restrict__ ew,
                          const int2* __restrict__ inv,
                          float* __restrict__ out) {
    int t = blockIdx.x;
    float2 w = ew[t];
    int2 pp = inv[t];
    const float4* y00 = (const float4*)(ybufs + (size_t)pp.x * H_DIM);
    const float4* y01 = (const float4*)(ybufs + (size_t)NPAIR * H_DIM + (size_t)pp.x * H_DIM);
    const float4* y10 = (const float4*)(ybufs + (size_t)pp.y * H_DIM);
    const float4* y11 = (const float4*)(ybufs + (size_t)NPAIR * H_DIM + (size_t)pp.y * H_DIM);
    float4* o = (float4*)(out + (size_t)t * H_DIM);
    for (int j = threadIdx.x; j < H_DIM / 4; j += blockDim.x) {
        float4 a0 = y00[j], a1 = y01[j], b0 = y10[j], b1 = y11[j];
        float4 r;
        r.x = w.x * (a0.x + a1.x) + w.y * (b0.x + b1.x);
        r.y = w.x * (a0.y + a1.y) + w.y * (b0.y + b1.y);
        r.z = w.x * (a0.z + a1.z) + w.y * (b0.z + b1.z);
        r.w = w.x * (a0.w + a1.w) + w.y * (b0.w + b1.w);
        o[j] = r;
    }
}

extern "C" void kernel_launch(void* const* d_in, const int* in_sizes, int n_in,
                              void* d_out, int out_size, void* d_ws, size_t ws_size,
                              hipStream_t stream) {
    const float* x  = (const float*)d_in[0];
    const float* gw = (const float*)d_in[1];
    const float* wg = (const float*)d_in[2];
    const float* wu = (const float*)d_in[3];
    const float* wd = (const float*)d_in[4];
    float* out = (float*)d_out;

    char* ws = (char*)d_ws;
    size_t o = 0;
    ushort* xb    = (ushort*)(ws + o); o += (size_t)T_TOK * H_DIM * 2;      //  8 MB
    ushort* hbuf  = (ushort*)(ws + o); o += (size_t)NPAIR * F_DIM * 2;      // 32 MB
    float*  ybufs = (float*) (ws + o); o += (size_t)2 * NPAIR * H_DIM * 4;  // 64 MB
    int*    ptok  = (int*)   (ws + o); o += NPAIR * 4;
    int2*   eidx  = (int2*)  (ws + o); o += T_TOK * 8;
    float2* ew    = (float2*)(ws + o); o += T_TOK * 8;
    int2*   inv   = (int2*)  (ws + o); o += T_TOK * 8;
    int*    cnt   = (int*)   (ws + o); o += 256;
    int*    cnt2  = (int*)   (ws + o); o += 256;
    int*    off   = (int*)   (ws + o); o += 256;

    hipMemsetAsync(cnt, 0, 256, stream);

    k_cvt_x <<<T_TOK * H_DIM / 8 / 256, 256, 0, stream>>>(x, xb);
    k_router<<<T_TOK / 4, 256, 0, stream>>>(x, gw, eidx, ew, cnt);
    k_off   <<<1, 64, 0, stream>>>(cnt, off, cnt2);
    k_fill  <<<T_TOK / 256, 256, 0, stream>>>(eidx, ew, off, cnt2, ptok, inv);

    dim3 g1(F_DIM / 64, E_NUM * 16);     // x: ntile(64), y: e*16 + mtile(256)
    k_gemm1<<<g1, 512, 0, stream>>>(xb, wg, wu, ptok, off, hbuf);
    dim3 g2(H_DIM / 128, E_NUM * 16);    // x: ntile(128), y: e*16 + mt*2 + kh
    k_gemm2<<<g2, 512, 0, stream>>>(hbuf, wd, off, ybufs);
    k_combine<<<T_TOK, 256, 0, stream>>>(ybufs, ew, inv, out);
}

// Round 18
// 555.919 us; speedup vs baseline: 1.1659x; 1.0314x over previous
//
#include <hip/hip_runtime.h>
#include <hip/hip_bf16.h>

// MiniMax MoE top-2, MI355X. T=2048, H=2048, F=4096, E=8.
// Round 18: R12-exact GEMM bodies (best structure, 573-575us plateau).
// Overhead consolidation: cvt_x fused into router; off+fill fused (1 block,
// LDS counters); gemm1 dead mt-tiles removed (y=E*8); single-pass gemm2.

#define T_TOK 2048
#define H_DIM 2048
#define F_DIM 4096
#define E_NUM 8
#define NPAIR (T_TOK * 2)

typedef __attribute__((ext_vector_type(8))) short short8;
typedef __attribute__((ext_vector_type(4))) float f32x4;

__device__ __forceinline__ unsigned short f2bf(float f) {
    unsigned u = __builtin_bit_cast(unsigned, f);
    u = (u + 0x7FFFu + ((u >> 16) & 1u)) >> 16;   // RNE
    return (unsigned short)u;
}

__device__ __forceinline__ uint4 pack8(float4 a, float4 b) {
    uint4 o;
    o.x = f2bf(a.x) | ((unsigned)f2bf(a.y) << 16);
    o.y = f2bf(a.z) | ((unsigned)f2bf(a.w) << 16);
    o.z = f2bf(b.x) | ((unsigned)f2bf(b.y) << 16);
    o.w = f2bf(b.z) | ((unsigned)f2bf(b.w) << 16);
    return o;
}

__device__ __forceinline__ uint2 pack4(float4 a) {
    uint2 o;
    o.x = f2bf(a.x) | ((unsigned)f2bf(a.y) << 16);
    o.y = f2bf(a.z) | ((unsigned)f2bf(a.w) << 16);
    return o;
}

__device__ __forceinline__ void gload16(const void* g, void* s) {
    __builtin_amdgcn_global_load_lds(
        (const __attribute__((address_space(1))) unsigned int*)g,
        (__attribute__((address_space(3))) unsigned int*)s, 16, 0, 0);
}

// ---- router + x->bf16 conversion (fused) -------------------------------
// 4 tokens/block, 1 wave each: convert row to xb, compute logits, top-2.
__global__ void k_router(const float* __restrict__ x, const float* __restrict__ gw,
                         ushort* __restrict__ xb,
                         int2* __restrict__ eidx, float2* __restrict__ ew,
                         int* __restrict__ cnt) {
    int t = blockIdx.x * 4 + (threadIdx.x >> 6);
    int lane = threadIdx.x & 63;
    const float* xr = x + (size_t)t * H_DIM;
    ushort* xbr = xb + (size_t)t * H_DIM;

    // convert: 8 floats/lane per iter, 4 iters -> full 2048-elem row
    #pragma unroll
    for (int j = 0; j < 4; j++) {
        int idx = (j * 64 + lane) * 8;
        const float4* p = (const float4*)(xr + idx);
        uint2 lo = pack4(p[0]), hi = pack4(p[1]);
        *(uint4*)(xbr + idx) = make_uint4(lo.x, lo.y, hi.x, hi.y);
    }

    float l[E_NUM];
    #pragma unroll
    for (int e = 0; e < E_NUM; e++) {
        const float* wr = gw + (size_t)e * H_DIM;
        float acc = 0.f;
        for (int i = lane; i < H_DIM; i += 64) acc += xr[i] * wr[i];
        #pragma unroll
        for (int o = 32; o; o >>= 1) acc += __shfl_xor(acc, o);
        l[e] = acc;
    }
    if (lane == 0) {
        int e0 = 0;
        #pragma unroll
        for (int e = 1; e < E_NUM; e++) if (l[e] > l[e0]) e0 = e;
        int e1 = -1;
        #pragma unroll
        for (int e = 0; e < E_NUM; e++) {
            if (e == e0) continue;
            if (e1 < 0 || l[e] > l[e1]) e1 = e;
        }
        float s1 = expf(l[e1] - l[e0]);
        float w0 = 1.f / (1.f + s1);
        float w1 = s1 * w0;
        eidx[t] = make_int2(e0, e1);
        ew[t]   = make_float2(w0, w1);
        atomicAdd(&cnt[e0], 1);
        atomicAdd(&cnt[e1], 1);
    }
}

// ---- offsets + expert-major scatter (fused, single block) --------------
// Pair order within an expert segment is arrival-order (LDS atomics), but
// pair VALUES (token id) and inv[t] are order-independent -> deterministic out.
__global__ void k_offfill(const int* __restrict__ cnt, int* __restrict__ off,
                          const int2* __restrict__ eidx,
                          int* __restrict__ ptok, int2* __restrict__ inv) {
    __shared__ int soff[E_NUM];
    __shared__ int scnt[E_NUM];
    if (threadIdx.x == 0) {
        int s = 0;
        for (int e = 0; e < E_NUM; e++) { soff[e] = s; off[e] = s; s += cnt[e]; scnt[e] = 0; }
        off[E_NUM] = s;
    }
    __syncthreads();
    for (int t = threadIdx.x; t < T_TOK; t += blockDim.x) {
        int2 e = eidx[t];
        int p0 = soff[e.x] + atomicAdd(&scnt[e.x], 1);
        ptok[p0] = t;
        int p1 = soff[e.y] + atomicAdd(&scnt[e.y], 1);
        ptok[p1] = t;
        inv[t] = make_int2(p0, p1);
    }
}

// ---- grouped GEMM1: h = silu(X Wg^T) * (X Wu^T)  (R12-exact body) ------
// BM=256 x BN=64 x BK=64, 512 thr = 8 waves (4m x 2n), wave tile 64x32.
// A: global_load_lds (wave-uniform base, pre-swizzled source).
__global__ __launch_bounds__(512, 4) void k_gemm1(
        const ushort* __restrict__ xb, const float* __restrict__ wg,
        const float* __restrict__ wu, const int* __restrict__ ptok,
        const int* __restrict__ off, ushort* __restrict__ hbuf) {
    __shared__ __align__(16) ushort As[256 * 64];   // 32 KB
    __shared__ __align__(16) ushort Bg[64 * 64];    //  8 KB
    __shared__ __align__(16) ushort Bu[64 * 64];    //  8 KB

    int e = blockIdx.y >> 3, mt = blockIdx.y & 7;   // ne <= 2048 -> mt < 8 exact
    int base = off[e], ne = off[e + 1] - base;
    int row0 = mt * 256;
    if (row0 >= ne) return;
    int nb = blockIdx.x * 64;

    int tid = threadIdx.x;
    int wv = tid >> 6, l = tid & 63;
    int lr = l & 15, lk = l >> 4;
    int wm = wv >> 1, wn = wv & 1;

    int wvu = __builtin_amdgcn_readfirstlane(wv);
    const ushort* srcA[4];
    int sslot = 8 * ((l & 7) ^ ((l >> 3) & 7));
    #pragma unroll
    for (int c = 0; c < 4; c++) {
        int r = (wvu * 4 + c) * 8 + (l >> 3);
        int pp = base + min(row0 + r, ne - 1);
        srcA[c] = xb + (size_t)ptok[pp] * H_DIM + sslot;
    }

    int brow = tid >> 3, bs = tid & 7;
    const float* wgrow = wg + ((size_t)e * F_DIM + nb + brow) * H_DIM + bs * 8;
    const float* wurow = wu + ((size_t)e * F_DIM + nb + brow) * H_DIM + bs * 8;
    int bo = brow * 64 + (((bs * 16) ^ ((brow & 7) << 4)) >> 1);

    int rsw = (lr & 7) << 4;

    f32x4 accg[4][2] = {}; f32x4 accu[4][2] = {};

    for (int kb = 0; kb < H_DIM; kb += 64) {
        __syncthreads();
        #pragma unroll
        for (int c = 0; c < 4; c++)
            gload16(srcA[c] + kb, (ushort*)As + (wvu * 4 + c) * 512);
        float4 g0 = *(const float4*)(wgrow + kb);
        float4 g1 = *(const float4*)(wgrow + kb + 4);
        *(uint4*)(&Bg[bo]) = pack8(g0, g1);
        float4 u0 = *(const float4*)(wurow + kb);
        float4 u1 = *(const float4*)(wurow + kb + 4);
        *(uint4*)(&Bu[bo]) = pack8(u0, u1);
        __syncthreads();

        #pragma unroll
        for (int kk = 0; kk < 2; kk++) {
            int kby = kk * 64 + lk * 16;
            short8 a[4];
            #pragma unroll
            for (int m = 0; m < 4; m++) {
                int row = wm * 64 + m * 16 + lr;
                a[m] = *(const short8*)(&As[(row * 128 + (kby ^ rsw)) >> 1]);
            }
            #pragma unroll
            for (int n = 0; n < 2; n++) {
                int rowb = wn * 32 + n * 16 + lr;
                int boff = (rowb * 128 + (kby ^ rsw)) >> 1;
                short8 bg8 = *(const short8*)(&Bg[boff]);
                short8 bu8 = *(const short8*)(&Bu[boff]);
                #pragma unroll
                for (int m = 0; m < 4; m++) {
                    accg[m][n] = __builtin_amdgcn_mfma_f32_16x16x32_bf16(a[m], bg8, accg[m][n], 0, 0, 0);
                    accu[m][n] = __builtin_amdgcn_mfma_f32_16x16x32_bf16(a[m], bu8, accu[m][n], 0, 0, 0);
                }
            }
        }
    }

    #pragma unroll
    for (int m = 0; m < 4; m++) {
        #pragma unroll
        for (int r = 0; r < 4; r++) {
            int lrow = wm * 64 + m * 16 + lk * 4 + r;
            if (row0 + lrow < ne) {
                size_t rb = (size_t)(base + row0 + lrow) * F_DIM + nb;
                #pragma unroll
                for (int n = 0; n < 2; n++) {
                    float g = accg[m][n][r], u = accu[m][n][r];
                    float hv = g / (1.f + __expf(-g)) * u;
                    hbuf[rb + wn * 32 + n * 16 + lr] = f2bf(hv);
                }
            }
        }
    }
}

// ---- grouped GEMM2: ybuf[p] = h[p] Wd^T  (R12-exact body) --------------
// BM=256 x BN=128 x BK=64, 512 thr = 8 waves (4m x 2n), wave tile 64x64.
__global__ __launch_bounds__(512, 2) void k_gemm2(
        const ushort* __restrict__ hbuf, const float* __restrict__ wd,
        const int* __restrict__ off, float* __restrict__ ybuf) {
    __shared__ __align__(16) ushort As[256 * 64];   // 32 KB
    __shared__ __align__(16) ushort Bs[128 * 64];   // 16 KB

    int e = blockIdx.y >> 3, mt = blockIdx.y & 7;
    int base = off[e], ne = off[e + 1] - base;
    int row0 = mt * 256;
    if (row0 >= ne) return;
    int nb = blockIdx.x * 128;

    int tid = threadIdx.x;
    int wv = tid >> 6, l = tid & 63;
    int lr = l & 15, lk = l >> 4;
    int wm = wv >> 1, wn = wv & 1;

    int wvu = __builtin_amdgcn_readfirstlane(wv);
    const ushort* srcA[4];
    int sslot = 8 * ((l & 7) ^ ((l >> 3) & 7));
    #pragma unroll
    for (int c = 0; c < 4; c++) {
        int r = (wvu * 4 + c) * 8 + (l >> 3);
        int pp = base + min(row0 + r, ne - 1);
        srcA[c] = hbuf + (size_t)pp * F_DIM + sslot;
    }

    int brow = tid >> 2, bs = tid & 3;
    const float* wdrow = wd + ((size_t)e * H_DIM + nb + brow) * F_DIM + bs * 16;
    int bsw = (brow & 7) << 4;
    int bo0 = brow * 64 + (((bs * 32) ^ bsw) >> 1);
    int bo1 = brow * 64 + (((bs * 32 + 16) ^ bsw) >> 1);

    int rsw = (lr & 7) << 4;

    f32x4 acc[4][4] = {};

    for (int kb = 0; kb < F_DIM; kb += 64) {
        __syncthreads();
        #pragma unroll
        for (int c = 0; c < 4; c++)
            gload16(srcA[c] + kb, (ushort*)As + (wvu * 4 + c) * 512);
        float4 b0 = *(const float4*)(wdrow + kb);
        float4 b1 = *(const float4*)(wdrow + kb + 4);
        float4 b2 = *(const float4*)(wdrow + kb + 8);
        float4 b3 = *(const float4*)(wdrow + kb + 12);
        *(uint4*)(&Bs[bo0]) = pack8(b0, b1);
        *(uint4*)(&Bs[bo1]) = pack8(b2, b3);
        __syncthreads();

        #pragma unroll
        for (int kk = 0; kk < 2; kk++) {
            int kby = kk * 64 + lk * 16;
            short8 a[4];
            #pragma unroll
            for (int m = 0; m < 4; m++) {
                int row = wm * 64 + m * 16 + lr;
                a[m] = *(const short8*)(&As[(row * 128 + (kby ^ rsw)) >> 1]);
            }
            #pragma unroll
            for (int n = 0; n < 4; n++) {
                int rowb = wn * 64 + n * 16 + lr;
                short8 b8 = *(const short8*)(&Bs[(rowb * 128 + (kby ^ rsw)) >> 1]);
                #pragma unroll
                for (int m = 0; m < 4; m++)
                    acc[m][n] = __builtin_amdgcn_mfma_f32_16x16x32_bf16(a[m], b8, acc[m][n], 0, 0, 0);
            }
        }
    }

    #pragma unroll
    for (int m = 0; m < 4; m++) {
        #pragma unroll
        for (int r = 0; r < 4; r++) {
            int lrow = wm * 64 + m * 16 + lk * 4 + r;
            if (row0 + lrow < ne) {
                float* yrow = ybuf + (size_t)(base + row0 + lrow) * H_DIM + nb;
                #pragma unroll
                for (int n = 0; n < 4; n++)
                    yrow[wn * 64 + n * 16 + lr] = acc[m][n][r];
            }
        }
    }
}

// ---- combine: out[t] = w0*y[p0] + w1*y[p1] -----------------------------
__global__ void k_combine(const float* __restrict__ ybuf,
                          const float2* __restrict__ ew,
                          const int2* __restrict__ inv,
                          float* __restrict__ out) {
    int t = blockIdx.x;
    float2 w = ew[t];
    int2 pp = inv[t];
    const float4* y0 = (const float4*)(ybuf + (size_t)pp.x * H_DIM);
    const float4* y1 = (const float4*)(ybuf + (size_t)pp.y * H_DIM);
    float4* o = (float4*)(out + (size_t)t * H_DIM);
    for (int j = threadIdx.x; j < H_DIM / 4; j += blockDim.x) {
        float4 a = y0[j], b = y1[j];
        float4 r;
        r.x = w.x * a.x + w.y * b.x;
        r.y = w.x * a.y + w.y * b.y;
        r.z = w.x * a.z + w.y * b.z;
        r.w = w.x * a.w + w.y * b.w;
        o[j] = r;
    }
}

extern "C" void kernel_launch(void* const* d_in, const int* in_sizes, int n_in,
                              void* d_out, int out_size, void* d_ws, size_t ws_size,
                              hipStream_t stream) {
    const float* x  = (const float*)d_in[0];
    const float* gw = (const float*)d_in[1];
    const float* wg = (const float*)d_in[2];
    const float* wu = (const float*)d_in[3];
    const float* wd = (const float*)d_in[4];
    float* out = (float*)d_out;

    char* ws = (char*)d_ws;
    size_t o = 0;
    ushort* xb   = (ushort*)(ws + o); o += (size_t)T_TOK * H_DIM * 2;   //  8 MB
    ushort* hbuf = (ushort*)(ws + o); o += (size_t)NPAIR * F_DIM * 2;   // 32 MB
    float*  ybuf = (float*) (ws + o); o += (size_t)NPAIR * H_DIM * 4;   // 32 MB
    int*    ptok = (int*)   (ws + o); o += NPAIR * 4;
    int2*   eidx = (int2*)  (ws + o); o += T_TOK * 8;
    float2* ew   = (float2*)(ws + o); o += T_TOK * 8;
    int2*   inv  = (int2*)  (ws + o); o += T_TOK * 8;
    int*    cnt  = (int*)   (ws + o); o += 256;
    int*    off  = (int*)   (ws + o); o += 256;

    hipMemsetAsync(cnt, 0, 256, stream);

    k_router <<<T_TOK / 4, 256, 0, stream>>>(x, gw, xb, eidx, ew, cnt);
    k_offfill<<<1, 256, 0, stream>>>(cnt, off, eidx, ptok, inv);

    dim3 g1(F_DIM / 64, E_NUM * 8);      // x: ntile(64), y: e*8 + mtile(256)
    k_gemm1<<<g1, 512, 0, stream>>>(xb, wg, wu, ptok, off, hbuf);
    dim3 g2(H_DIM / 128, E_NUM * 8);     // x: ntile(128), y: e*8 + mtile(256)
    k_gemm2<<<g2, 512, 0, stream>>>(hbuf, wd, off, ybuf);
    k_combine<<<T_TOK, 256, 0, stream>>>(ybuf, ew, inv, out);
}